// Round 1
// baseline (135.551 us; speedup 1.0000x reference)
//
#include <hip/hip_runtime.h>
#include <hip/hip_bf16.h>

#define B_N 2048
#define D_V 8
#define F_D 256
#define TILE 128
#define BC 64
#define LSTR 264   // padded LDS row stride (shorts); 264*2B=528B -> conflict-free b128 reads

// sqrt(2*log2(e)) : zn scaled by this => MFMA acc = 2*log2(e)*dot => exp(2*dot) = exp2(acc)
#define SCALE_F 1.69864364f

#if defined(__has_builtin)
#  if __has_builtin(__builtin_amdgcn_exp2f)
#    define EXP2F(x) __builtin_amdgcn_exp2f(x)
#  else
#    define EXP2F(x) exp2f(x)
#  endif
#else
#  define EXP2F(x) exp2f(x)
#endif

typedef __attribute__((ext_vector_type(8))) short short8;
typedef __attribute__((ext_vector_type(4))) float floatx4;

__device__ inline unsigned short f2bf(float f) {
    __hip_bfloat16 h = __float2bfloat16(f);
    return *reinterpret_cast<unsigned short*>(&h);
}

__device__ inline float wave_reduce_sum(float v) {
    #pragma unroll
    for (int off = 1; off < 64; off <<= 1)
        v += __shfl_xor(v, off, 64);
    return v;
}

__device__ inline float wave_reduce_max(float v) {
    #pragma unroll
    for (int off = 1; off < 64; off <<= 1)
        v = fmaxf(v, __shfl_xor(v, off, 64));
    return v;
}

// ---------------------------------------------------------------------------
// Kernel 1: fused normalize + pos. Block = 256 threads (4 waves) handles 4
// samples (32 rows). Each wave normalizes its sample's 8 rows (writing scaled
// bf16 zn to global [d][b][f] AND to LDS), then waves 0/1 compute pos for 2
// samples each via MFMA straight from LDS. Also zero-inits ns8 + ticket cnt.
// ---------------------------------------------------------------------------
__global__ __launch_bounds__(256)
void np_kernel(const float* __restrict__ z, unsigned short* __restrict__ zn,
               float* __restrict__ ns8, float* __restrict__ pos,
               unsigned int* __restrict__ cnt) {
    __shared__ __align__(16) unsigned short Zs[32 * LSTR];  // 16.9 KB
    int tid = threadIdx.x;
    int gid = blockIdx.x * 256 + tid;
    if (gid < D_V * B_N) ns8[gid] = 0.0f;
    if (gid == 0) *cnt = 0u;

    int w = tid >> 6, lane = tid & 63;
    int b = blockIdx.x * 4 + w;  // this wave's sample
    #pragma unroll
    for (int k = 0; k < 8; k++) {
        const float4 v = ((const float4*)(z + ((size_t)b * 8 + k) * F_D))[lane];
        float ss = v.x * v.x + v.y * v.y + v.z * v.z + v.w * v.w;
        ss = wave_reduce_sum(ss);
        float inv = SCALE_F / fmaxf(sqrtf(ss), 1e-12f);
        ushort4 o;
        o.x = f2bf(v.x * inv);
        o.y = f2bf(v.y * inv);
        o.z = f2bf(v.z * inv);
        o.w = f2bf(v.w * inv);
        ((ushort4*)(zn + (size_t)k * (B_N * F_D) + (size_t)b * F_D))[lane] = o;
        *(ushort4*)(&Zs[(w * 8 + k) * LSTR + lane * 4]) = o;
    }
    __syncthreads();

    // pos: wave 0 -> local samples 0,1 ; wave 1 -> local samples 2,3
    if (w < 2) {
        int q = lane >> 4, li = lane & 15;
        int lr = (w * 2 + (li >> 3)) * 8 + (li & 7);  // local row: sample*8 + view
        short8 a[8];
        #pragma unroll
        for (int kk = 0; kk < 8; kk++)
            a[kk] = *(const short8*)(&Zs[lr * LSTR + kk * 32 + q * 8]);
        floatx4 acc = {0.f, 0.f, 0.f, 0.f};
        #pragma unroll
        for (int kk = 0; kk < 8; kk++)
            acc = __builtin_amdgcn_mfma_f32_16x16x32_bf16(a[kk], a[kk], acc, 0, 0, 0);
        float p0 = 0.f, p1 = 0.f;
        #pragma unroll
        for (int r = 0; r < 4; r++) {
            int row = q * 4 + r, col = li;
            bool same_sample = (row >> 3) == (col >> 3);
            if (same_sample && row != col) {
                float e = EXP2F(acc[r]);   // acc already = 2*log2e*dot
                if (row < 8) p0 += e; else p1 += e;
            }
        }
        p0 = wave_reduce_sum(p0);
        p1 = wave_reduce_sum(p1);
        if (lane == 0) {
            int s0 = blockIdx.x * 4 + w * 2;
            pos[s0] = p0;
            pos[s0 + 1] = p1;
        }
    }
}

// ---------------------------------------------------------------------------
// Kernel 2: symmetric-halved neg + fused final reduction.
// 1-D grid 1088 = 136 upper-tri tiles x 8 views; d = bid&7 pins each view to
// one XCD (1 MB working set, L2-resident). Block = 128 threads (2 waves),
// each wave owns 64 A-rows with K=256 resident in 128 VGPRs; B staged in LDS
// 64 cols at a time. Epilogue: e = v_exp(acc) directly (scale pre-folded).
// Last block (ticket) computes the loss scalar.
// ---------------------------------------------------------------------------
__global__ __launch_bounds__(128, 2)
void neg_kernel(const unsigned short* __restrict__ zn,
                float* __restrict__ ns8,
                const float* __restrict__ pos,
                float* __restrict__ out,
                unsigned int* __restrict__ cnt) {
    __shared__ __align__(16) unsigned short Bs[BC * LSTR];  // 33.8 KB
    __shared__ unsigned int tk_s;
    const int bid = blockIdx.x;
    const int d = bid & 7;            // view == XCD (heuristic; perf-only)
    int trem = bid >> 3;              // 0..135 -> (i,j), i<=j
    int i = 0;
    while (trem >= 16 - i) { trem -= 16 - i; ++i; }
    const int j = i + trem;
    const bool diag = (i == j);
    const unsigned short* Z = zn + (size_t)d * (B_N * F_D);
    int tid = threadIdx.x, w = tid >> 6, lane = tid & 63;
    int q = lane >> 4, li = lane & 15;
    int r0 = i * TILE + w * 64;       // this wave's 64 A-rows

    short8 a[4][8];
    #pragma unroll
    for (int s = 0; s < 4; s++)
        #pragma unroll
        for (int kk = 0; kk < 8; kk++)
            a[s][kk] = *(const short8*)(Z + (size_t)(r0 + s * 16 + li) * F_D + kk * 32 + q * 8);

    float rs[4][4];
    #pragma unroll
    for (int s = 0; s < 4; s++)
        #pragma unroll
        for (int r = 0; r < 4; r++) rs[s][r] = 0.f;
    float cs[8];

    #pragma unroll
    for (int stage = 0; stage < 2; ++stage) {
        int c0 = j * TILE + stage * BC;
        __syncthreads();
        // stage 64 rows x 256 shorts: 2048 16B-chunks, 16 per thread
        #pragma unroll
        for (int it = 0; it < 16; ++it) {
            int idx = it * 128 + tid;
            int row = idx >> 5, kc = idx & 31;
            *(short8*)(&Bs[row * LSTR + kc * 8]) =
                *(const short8*)(Z + (size_t)(c0 + row) * F_D + kc * 8);
        }
        __syncthreads();
        #pragma unroll
        for (int ct = 0; ct < 4; ++ct) {
            short8 bf[8];
            #pragma unroll
            for (int kk = 0; kk < 8; kk++)
                bf[kk] = *(const short8*)(&Bs[(ct * 16 + li) * LSTR + kk * 32 + q * 8]);
            floatx4 acc[4];
            #pragma unroll
            for (int s = 0; s < 4; s++) acc[s] = (floatx4){0.f, 0.f, 0.f, 0.f};
            #pragma unroll
            for (int kk = 0; kk < 8; kk++)
                #pragma unroll
                for (int s = 0; s < 4; s++)
                    acc[s] = __builtin_amdgcn_mfma_f32_16x16x32_bf16(a[s][kk], bf[kk], acc[s], 0, 0, 0);
            // C/D layout: col = li, row(within set) = q*4 + r
            int gcol = c0 + ct * 16 + li;
            float csum = 0.f;
            #pragma unroll
            for (int s = 0; s < 4; s++) {
                #pragma unroll
                for (int r = 0; r < 4; r++) {
                    float e = EXP2F(acc[s][r]);        // exp(2*dot), 1 trans op
                    if (diag) {                        // uniform branch: 16/136 blocks
                        int grow = r0 + s * 16 + q * 4 + r;
                        if (grow == gcol) e = 0.f;
                    }
                    rs[s][r] += e;
                    csum += e;
                }
            }
            cs[stage * 4 + ct] = csum;  // static index (both loops unrolled)
        }
    }

    // row sums: reduce across the 16 column-lanes; all 64 lanes then each
    // write one row's atomic (li selects (s,r) via static compare-select)
    #pragma unroll
    for (int off = 1; off < 16; off <<= 1)
        #pragma unroll
        for (int s = 0; s < 4; s++)
            #pragma unroll
            for (int r = 0; r < 4; r++)
                rs[s][r] += __shfl_xor(rs[s][r], off, 64);
    {
        float rv = 0.f;
        #pragma unroll
        for (int s = 0; s < 4; s++)
            #pragma unroll
            for (int r = 0; r < 4; r++)
                if (li == s * 4 + r) rv = rs[s][r];
        int grow = r0 + (li >> 2) * 16 + q * 4 + (li & 3);
        atomicAdd(&ns8[d * B_N + grow], rv);
    }

    // col sums (mirrored tile coverage): cross-q reduce once at the end
    if (!diag) {
        #pragma unroll
        for (int c = 0; c < 8; c++) {
            cs[c] += __shfl_xor(cs[c], 16, 64);
            cs[c] += __shfl_xor(cs[c], 32, 64);
        }
        float v0 = 0.f, v1 = 0.f;
        #pragma unroll
        for (int c = 0; c < 4; c++)
            if (q == c) { v0 = cs[c]; v1 = cs[c + 4]; }
        atomicAdd(&ns8[d * B_N + j * TILE + q * 16 + li], v0);
        atomicAdd(&ns8[d * B_N + j * TILE + 64 + q * 16 + li], v1);
    }

    // ---- last-block ticket: fused final reduction ----
    __threadfence();
    if (tid == 0) tk_s = atomicAdd(cnt, 1u);
    __syncthreads();
    if (tk_s != gridDim.x - 1) return;
    __threadfence();

    float* fr = (float*)Bs;  // reuse LDS as scratch
    float vals[16];
    float lmax = -1e30f;
    #pragma unroll
    for (int t2 = 0; t2 < 16; t2++) {
        int idx = t2 * 128 + tid;
        float nsum = 0.f;
        #pragma unroll
        for (int dd = 0; dd < D_V; dd++) nsum += ns8[dd * B_N + idx];
        float p = pos[idx];
        float l = p / (p + nsum * (1.0f / (float)(B_N - 1)));
        vals[t2] = l;
        lmax = fmaxf(lmax, l);
    }
    lmax = wave_reduce_max(lmax);
    if (lane == 0) fr[w] = lmax;
    __syncthreads();
    float m = fmaxf(fr[0], fr[1]);
    float se = 0.f, sl = 0.f;
    #pragma unroll
    for (int t2 = 0; t2 < 16; t2++) {
        se += expf(vals[t2] - m);
        sl += vals[t2];
    }
    se = wave_reduce_sum(se);
    sl = wave_reduce_sum(sl);
    if (lane == 0) { fr[2 + w] = se; fr[6 + w] = sl; }
    __syncthreads();
    if (tid == 0)
        out[0] = m + logf(fr[2] + fr[3]) - (fr[6] + fr[7]) * (1.0f / (float)B_N);
}

extern "C" void kernel_launch(void* const* d_in, const int* in_sizes, int n_in,
                              void* d_out, int out_size, void* d_ws, size_t ws_size,
                              hipStream_t stream) {
    const float* z = (const float*)d_in[0];
    float* out = (float*)d_out;
    unsigned short* zn = (unsigned short*)d_ws;                        // 8 MB bf16 (pre-scaled)
    float* ns8 = (float*)((char*)d_ws + (size_t)D_V * B_N * F_D * 2);  // 64 KB
    float* pos = ns8 + D_V * B_N;                                      // 8 KB
    unsigned int* cnt = (unsigned int*)(pos + B_N);                    // 4 B ticket

    np_kernel<<<dim3(512), 256, 0, stream>>>(z, zn, ns8, pos, cnt);
    neg_kernel<<<dim3(1088), 128, 0, stream>>>(zn, ns8, pos, out, cnt);
}